// Round 2
// baseline (443.213 us; speedup 1.0000x reference)
//
#include <hip/hip_runtime.h>
#include <stdint.h>

typedef int v4i __attribute__((ext_vector_type(4)));

__device__ __forceinline__ int clamp_i8(int v) {
    return v < -128 ? -128 : (v > 127 ? 127 : v);
}

__device__ __forceinline__ void async_load16(const void* g, void* l) {
    __builtin_amdgcn_global_load_lds(
        (const __attribute__((address_space(1))) void*)g,
        (__attribute__((address_space(3))) void*)l, 16, 0, 0);
}

// ---------------- pre-pass 1: quantize fp32 input -> int8 ----------------
__global__ void quant_input_kernel(const float* __restrict__ x, int8_t* __restrict__ q,
                                   const float* __restrict__ scale_p,
                                   const int* __restrict__ zp_p, int n4) {
    int t = blockIdx.x * blockDim.x + threadIdx.x;
    if (t >= n4) return;
    const float s = *scale_p;
    const int zp = *zp_p;
    float4 v = ((const float4*)x)[t];
    int q0 = clamp_i8((int)rintf(v.x / s) + zp);
    int q1 = clamp_i8((int)rintf(v.y / s) + zp);
    int q2 = clamp_i8((int)rintf(v.z / s) + zp);
    int q3 = clamp_i8((int)rintf(v.w / s) + zp);
    int packed = (q0 & 255) | ((q1 & 255) << 8) | ((q2 & 255) << 16) | ((q3 & 255) << 24);
    ((int*)q)[t] = packed;
}

// ---------------- pre-pass 2: pack int32 weight -> int8 ----------------
__global__ void pack_weight_kernel(const int* __restrict__ w, int8_t* __restrict__ q, int n4) {
    int t = blockIdx.x * blockDim.x + threadIdx.x;
    if (t >= n4) return;
    int4 v = ((const int4*)w)[t];
    int packed = (v.x & 255) | ((v.y & 255) << 8) | ((v.z & 255) << 16) | ((v.w & 255) << 24);
    ((int*)q)[t] = packed;
}

// ---------------- main GEMM: C[i][j] = sum_k A[i][k] * W[j][k] ----------------
// A: [N][K] int8 row-major, W: [OUT][K] int8 row-major (both k-contiguous)
// 128x128 block tile, BK=64; 4 waves in 2x2, each wave 64x64 via 4x4 MFMA accs.
#define BM 128
#define BN 128
#define BK 64

__global__ __launch_bounds__(256) void gemm_i8_kernel(
    const int8_t* __restrict__ A, const int8_t* __restrict__ W,
    const int* __restrict__ bias, int* __restrict__ C,
    const float* __restrict__ oscale_p, const int* __restrict__ ozp_p,
    int N, int K, int M) {
    __shared__ int8_t lA[BM * BK];  // 8 KiB
    __shared__ int8_t lW[BN * BK];  // 8 KiB

    const int tid = threadIdx.x;
    const int lane = tid & 63;
    const int w = tid >> 6;        // wave 0..3
    const int wm = w & 1;          // wave row
    const int wn = w >> 1;         // wave col
    const int qm = lane & 15;      // fragment row/col within 16
    const int qk = lane >> 4;      // k-quad 0..3

    const int bm = blockIdx.y * BM;
    const int bn = blockIdx.x * BN;

    // staging: wave w covers rows [w*32, w*32+32) of the tile, two 1024B chunks.
    // LDS offset = w*2048 + c*1024 + lane*16 -> row = w*32 + c*16 + lane/4, col = (lane&3)*16
    const int s_row = w * 32 + (lane >> 2);
    const int s_col = (lane & 3) * 16;
    const int8_t* gA = A + (int64_t)(bm + s_row) * K + s_col;
    const int8_t* gW = W + (int64_t)(bn + s_row) * K + s_col;
    int8_t* lA0 = &lA[w * 2048];
    int8_t* lW0 = &lW[w * 2048];
    const int64_t rowskip = (int64_t)16 * K;  // chunk c=1 is +16 rows

    v4i acc[4][4];
#pragma unroll
    for (int i = 0; i < 4; i++)
#pragma unroll
        for (int j = 0; j < 4; j++) acc[i][j] = (v4i){0, 0, 0, 0};

    for (int kt = 0; kt < K; kt += BK) {
        async_load16(gA + kt, lA0);
        async_load16(gA + kt + rowskip, lA0 + 1024);
        async_load16(gW + kt, lW0);
        async_load16(gW + kt + rowskip, lW0 + 1024);
        __syncthreads();

        v4i af[4], bf[4];
#pragma unroll
        for (int ms = 0; ms < 4; ms++)
            af[ms] = *(const v4i*)&lA[(wm * 64 + ms * 16 + qm) * BK + qk * 16];
#pragma unroll
        for (int ns = 0; ns < 4; ns++)
            bf[ns] = *(const v4i*)&lW[(wn * 64 + ns * 16 + qm) * BK + qk * 16];

#pragma unroll
        for (int ms = 0; ms < 4; ms++)
#pragma unroll
            for (int ns = 0; ns < 4; ns++)
                acc[ms][ns] = __builtin_amdgcn_mfma_i32_16x16x64_i8(af[ms], bf[ns],
                                                                    acc[ms][ns], 0, 0, 0);
        __syncthreads();
    }

    // epilogue: requantize, store as int32 (harness reads output as np.int32)
    const float os = *oscale_p;
    const int ozp = *ozp_p;
#pragma unroll
    for (int ns = 0; ns < 4; ns++) {
        const int gn = bn + wn * 64 + ns * 16 + qm;       // col = lane&15
        const int bv = bias[gn];
#pragma unroll
        for (int ms = 0; ms < 4; ms++) {
            const int gm = bm + wm * 64 + ms * 16 + qk * 4;  // row = quad*4 + reg
            v4i a = acc[ms][ns];
#pragma unroll
            for (int r = 0; r < 4; r++) {
                int v = a[r] + bv;
                int q = (int)rintf((float)v / os) + ozp;
                q = clamp_i8(q);
                C[(int64_t)(gm + r) * M + gn] = q;
            }
        }
    }
}

extern "C" void kernel_launch(void* const* d_in, const int* in_sizes, int n_in,
                              void* d_out, int out_size, void* d_ws, size_t ws_size,
                              hipStream_t stream) {
    const float* x = (const float*)d_in[0];
    const int* wgt = (const int*)d_in[1];
    const int* bias = (const int*)d_in[2];
    const float* in_scale = (const float*)d_in[3];
    const int* in_zp = (const int*)d_in[4];
    const float* out_scale = (const float*)d_in[5];
    const int* out_zp = (const int*)d_in[6];

    const int64_t x_elems = (int64_t)in_sizes[0];  // N*K
    const int OUT = in_sizes[2];                   // bias length
    const int K = in_sizes[1] / OUT;               // IN
    const int N = (int)(x_elems / K);

    int8_t* qA = (int8_t*)d_ws;
    int8_t* qW = qA + x_elems;  // N*K bytes

    {
        int n4 = (int)(x_elems / 4);
        quant_input_kernel<<<(n4 + 255) / 256, 256, 0, stream>>>(x, qA, in_scale, in_zp, n4);
    }
    {
        int n4 = (int)(((int64_t)OUT * K) / 4);
        pack_weight_kernel<<<(n4 + 255) / 256, 256, 0, stream>>>(wgt, qW, n4);
    }
    dim3 grid(OUT / BN, N / BM);
    gemm_i8_kernel<<<grid, 256, 0, stream>>>(qA, qW, bias, (int*)d_out,
                                             out_scale, out_zp, N, K, OUT);
}

// Round 3
// 427.784 us; speedup vs baseline: 1.0361x; 1.0361x over previous
//
#include <hip/hip_runtime.h>
#include <stdint.h>

typedef int v4i __attribute__((ext_vector_type(4)));
typedef int v16i __attribute__((ext_vector_type(16)));

__device__ __forceinline__ int clamp_i8(int v) {
    return v < -128 ? -128 : (v > 127 ? 127 : v);
}

__device__ __forceinline__ void async_load16(const void* g, void* l) {
    __builtin_amdgcn_global_load_lds(
        (const __attribute__((address_space(1))) void*)g,
        (__attribute__((address_space(3))) void*)l, 16, 0, 0);
}

// ---------------- pre-pass 1: quantize fp32 input -> int8 ----------------
__global__ void quant_input_kernel(const float* __restrict__ x, int8_t* __restrict__ q,
                                   const float* __restrict__ scale_p,
                                   const int* __restrict__ zp_p, int n4) {
    int t = blockIdx.x * blockDim.x + threadIdx.x;
    if (t >= n4) return;
    const float inv = 1.0f / *scale_p;  // mul-by-recip: <=1ulp vs div; off-by-1 quant flips are ~1e-7 rare and shift output by <=0.04
    const int zp = *zp_p;
    float4 v = ((const float4*)x)[t];
    int q0 = clamp_i8((int)rintf(v.x * inv) + zp);
    int q1 = clamp_i8((int)rintf(v.y * inv) + zp);
    int q2 = clamp_i8((int)rintf(v.z * inv) + zp);
    int q3 = clamp_i8((int)rintf(v.w * inv) + zp);
    int packed = (q0 & 255) | ((q1 & 255) << 8) | ((q2 & 255) << 16) | ((q3 & 255) << 24);
    ((int*)q)[t] = packed;
}

// ---------------- pre-pass 2: pack int32 weight -> int8 ----------------
__global__ void pack_weight_kernel(const int* __restrict__ w, int8_t* __restrict__ q, int n4) {
    int t = blockIdx.x * blockDim.x + threadIdx.x;
    if (t >= n4) return;
    int4 v = ((const int4*)w)[t];
    int packed = (v.x & 255) | ((v.y & 255) << 8) | ((v.z & 255) << 16) | ((v.w & 255) << 24);
    ((int*)q)[t] = packed;
}

// ---------------- main GEMM: C[i][j] = sum_k A[i][k] * W[j][k] ----------------
// 256x128 block tile, BK=64; 4 waves 2x2, wave tile 128x64 via 4x2 of 32x32x32 MFMA.
// ops/LDS-byte = 87 (vs 64 at 64x64 wave tile) -> LDS ~balanced with MFMA pipe.
#define BM 256
#define BN 128
#define BK 64

__global__ __launch_bounds__(256, 2) void gemm_i8_kernel(
    const int8_t* __restrict__ A, const int8_t* __restrict__ W,
    const int* __restrict__ bias, int* __restrict__ C,
    const float* __restrict__ oscale_p, const int* __restrict__ ozp_p,
    int N, int K, int M) {
    __shared__ int8_t lA[BM * BK];  // 16 KiB
    __shared__ int8_t lB[BN * BK];  // 8 KiB

    const int tid = threadIdx.x;
    const int lane = tid & 63;
    const int w = tid >> 6;   // wave 0..3
    const int wm = w >> 1;    // wave row (0..1), tile rows wm*128
    const int wn = w & 1;     // wave col (0..1), tile cols wn*64

    const int bm = blockIdx.y * BM;
    const int bn = blockIdx.x * BN;

    // --- staging: A rows w*64..w*64+63 (4 insts), B rows w*32..w*32+31 (2 insts)
    // LDS offset = wavebase + c*1024 + lane*16 -> row = base_row + c*16 + lane/4, col = (lane&3)*16
    const int s_sub = lane >> 2;          // 0..15
    const int s_col = (lane & 3) * 16;    // 0/16/32/48
    const int8_t* gA = A + (int64_t)(bm + w * 64 + s_sub) * K + s_col;
    const int8_t* gB = W + (int64_t)(bn + w * 32 + s_sub) * K + s_col;
    int8_t* lA0 = &lA[w * 4096];
    int8_t* lB0 = &lB[w * 2048];
    const int64_t rs = (int64_t)16 * K;   // +16 rows per chunk

    // --- fragment LDS offsets (A/B: [m=lane&31][k=(lane>>5)*16+j], row-major stride 64)
    const int m0 = lane & 31;
    const int kh = (lane >> 5) * 16;

    v16i acc[4][2];
#pragma unroll
    for (int i = 0; i < 4; i++)
#pragma unroll
        for (int j = 0; j < 2; j++)
#pragma unroll
            for (int r = 0; r < 16; r++) acc[i][j][r] = 0;

    for (int kt = 0; kt < K; kt += BK) {
        async_load16(gA, lA0);
        async_load16(gA + rs, lA0 + 1024);
        async_load16(gA + 2 * rs, lA0 + 2048);
        async_load16(gA + 3 * rs, lA0 + 3072);
        async_load16(gB, lB0);
        async_load16(gB + rs, lB0 + 1024);
        gA += BK;
        gB += BK;
        __syncthreads();

#pragma unroll
        for (int k0 = 0; k0 < BK; k0 += 32) {
            v4i af[4], bf[2];
#pragma unroll
            for (int ms = 0; ms < 4; ms++)
                af[ms] = *(const v4i*)&lA[(wm * 128 + ms * 32 + m0) * BK + k0 + kh];
#pragma unroll
            for (int ns = 0; ns < 2; ns++)
                bf[ns] = *(const v4i*)&lB[(wn * 64 + ns * 32 + m0) * BK + k0 + kh];

#pragma unroll
            for (int ms = 0; ms < 4; ms++)
#pragma unroll
                for (int ns = 0; ns < 2; ns++)
                    acc[ms][ns] = __builtin_amdgcn_mfma_i32_32x32x32_i8(
                        af[ms], bf[ns], acc[ms][ns], 0, 0, 0);
        }
        __syncthreads();
    }

    // --- epilogue: requantize, store int32
    // C/D layout (32x32): col = lane&31, row = (reg&3) + 8*(reg>>2) + 4*(lane>>5)
    const float inv_os = 1.0f / *oscale_p;  // os=4096 -> exact; general case off-by-1 within threshold
    const int ozp = *ozp_p;
    const int rbase = 4 * (lane >> 5);
#pragma unroll
    for (int ns = 0; ns < 2; ns++) {
        const int gn = bn + wn * 64 + ns * 32 + m0;
        const int bv = bias[gn];
#pragma unroll
        for (int ms = 0; ms < 4; ms++) {
            const int gm0 = bm + wm * 128 + ms * 32 + rbase;
            v16i a = acc[ms][ns];
#pragma unroll
            for (int reg = 0; reg < 16; reg++) {
                const int row = (reg & 3) + 8 * (reg >> 2);
                int v = a[reg] + bv;
                int q = (int)rintf((float)v * inv_os) + ozp;
                q = clamp_i8(q);
                C[(int64_t)(gm0 + row) * M + gn] = q;
            }
        }
    }
}

extern "C" void kernel_launch(void* const* d_in, const int* in_sizes, int n_in,
                              void* d_out, int out_size, void* d_ws, size_t ws_size,
                              hipStream_t stream) {
    const float* x = (const float*)d_in[0];
    const int* wgt = (const int*)d_in[1];
    const int* bias = (const int*)d_in[2];
    const float* in_scale = (const float*)d_in[3];
    const int* in_zp = (const int*)d_in[4];
    const float* out_scale = (const float*)d_in[5];
    const int* out_zp = (const int*)d_in[6];

    const int64_t x_elems = (int64_t)in_sizes[0];  // N*K
    const int OUT = in_sizes[2];                   // bias length
    const int K = in_sizes[1] / OUT;               // IN
    const int N = (int)(x_elems / K);

    int8_t* qA = (int8_t*)d_ws;
    int8_t* qW = qA + x_elems;

    {
        int n4 = (int)(x_elems / 4);
        quant_input_kernel<<<(n4 + 255) / 256, 256, 0, stream>>>(x, qA, in_scale, in_zp, n4);
    }
    {
        int n4 = (int)(((int64_t)OUT * K) / 4);
        pack_weight_kernel<<<(n4 + 255) / 256, 256, 0, stream>>>(wgt, qW, n4);
    }
    dim3 grid(OUT / BN, N / BM);
    gemm_i8_kernel<<<grid, 256, 0, stream>>>(qA, qW, bias, (int*)d_out,
                                             out_scale, out_zp, N, K, OUT);
}

// Round 4
// 424.452 us; speedup vs baseline: 1.0442x; 1.0079x over previous
//
#include <hip/hip_runtime.h>
#include <stdint.h>

typedef int v4i __attribute__((ext_vector_type(4)));
typedef int v16i __attribute__((ext_vector_type(16)));

__device__ __forceinline__ int clamp_i8(int v) {
    return v < -128 ? -128 : (v > 127 ? 127 : v);
}

__device__ __forceinline__ void async_load16(const void* g, void* l) {
    __builtin_amdgcn_global_load_lds(
        (const __attribute__((address_space(1))) void*)g,
        (__attribute__((address_space(3))) void*)l, 16, 0, 0);
}

// ---------------- pre-pass 1: quantize fp32 input -> int8 ----------------
__global__ void quant_input_kernel(const float* __restrict__ x, int8_t* __restrict__ q,
                                   const float* __restrict__ scale_p,
                                   const int* __restrict__ zp_p, int n4) {
    int t = blockIdx.x * blockDim.x + threadIdx.x;
    if (t >= n4) return;
    const float inv = 1.0f / *scale_p;
    const int zp = *zp_p;
    float4 v = ((const float4*)x)[t];
    int q0 = clamp_i8((int)rintf(v.x * inv) + zp);
    int q1 = clamp_i8((int)rintf(v.y * inv) + zp);
    int q2 = clamp_i8((int)rintf(v.z * inv) + zp);
    int q3 = clamp_i8((int)rintf(v.w * inv) + zp);
    int packed = (q0 & 255) | ((q1 & 255) << 8) | ((q2 & 255) << 16) | ((q3 & 255) << 24);
    ((int*)q)[t] = packed;
}

// ---------------- pre-pass 2: pack int32 weight -> int8 ----------------
__global__ void pack_weight_kernel(const int* __restrict__ w, int8_t* __restrict__ q, int n4) {
    int t = blockIdx.x * blockDim.x + threadIdx.x;
    if (t >= n4) return;
    int4 v = ((const int4*)w)[t];
    int packed = (v.x & 255) | ((v.y & 255) << 8) | ((v.z & 255) << 16) | ((v.w & 255) << 24);
    ((int*)q)[t] = packed;
}

// ---------------- main GEMM: C[i][j] = sum_k A[i][k] * W[j][k] ----------------
// 256x128 block tile, BK=64; 4 waves 2x2, wave tile 128x64 via 4x2 of 32x32x32 MFMA.
// LDS layout XOR-swizzled: tile (row r, 16B-chunk c) lives at physical chunk
// c ^ ((r>>1)&3). Bank-group of a b128 read = (4r + c^((r>>1)&3)) mod 8 -> a
// permutation over every 8 consecutive rows -> conflict-free ds_read_b128.
// Swizzle applied at staging by permuting each lane's GLOBAL source column
// (LDS dest of global_load_lds is fixed linear lane*16).
#define BM 256
#define BN 128
#define BK 64

__global__ __launch_bounds__(256, 2) void gemm_i8_kernel(
    const int8_t* __restrict__ A, const int8_t* __restrict__ W,
    const int* __restrict__ bias, int* __restrict__ C,
    const float* __restrict__ oscale_p, const int* __restrict__ ozp_p,
    int N, int K, int M) {
    __shared__ int8_t lA[BM * BK];  // 16 KiB
    __shared__ int8_t lB[BN * BK];  // 8 KiB

    const int tid = threadIdx.x;
    const int lane = tid & 63;
    const int w = tid >> 6;   // wave 0..3
    const int wm = w >> 1;    // wave row (0..1), tile rows wm*128
    const int wn = w & 1;     // wave col (0..1), tile cols wn*64

    const int bm = blockIdx.y * BM;
    const int bn = blockIdx.x * BN;

    // --- staging: lane l covers LDS row (chunkbase + l>>2), physical chunk l&3.
    // Global source chunk = (l&3) ^ ((s_sub>>1)&3)  [the swizzle].
    const int s_sub = lane >> 2;                                  // 0..15
    const int s_col = (((lane & 3) ^ ((s_sub >> 1) & 3))) * 16;   // swizzled col
    const int8_t* gA = A + (int64_t)(bm + w * 64 + s_sub) * K + s_col;
    const int8_t* gB = W + (int64_t)(bn + w * 32 + s_sub) * K + s_col;
    int8_t* lA0 = &lA[w * 4096];
    int8_t* lB0 = &lB[w * 2048];
    const int64_t rs = (int64_t)16 * K;   // +16 rows per chunk

    // --- fragment identities (A/B: [m=lane&31][k=(lane>>5)*16+j])
    const int m0 = lane & 31;
    const int rsw = (m0 >> 1) & 3;   // row-swizzle term (bits 1-2 of any frag row)
    const int chi = lane >> 5;       // k-half chunk index contribution

    v16i acc[4][2];
#pragma unroll
    for (int i = 0; i < 4; i++)
#pragma unroll
        for (int j = 0; j < 2; j++)
#pragma unroll
            for (int r = 0; r < 16; r++) acc[i][j][r] = 0;

    for (int kt = 0; kt < K; kt += BK) {
        async_load16(gA, lA0);
        async_load16(gA + rs, lA0 + 1024);
        async_load16(gA + 2 * rs, lA0 + 2048);
        async_load16(gA + 3 * rs, lA0 + 3072);
        async_load16(gB, lB0);
        async_load16(gB + rs, lB0 + 1024);
        gA += BK;
        gB += BK;
        __syncthreads();

#pragma unroll
        for (int k0 = 0; k0 < BK; k0 += 32) {
            const int cb = k0 >> 4;  // 0 or 2
            v4i af[4], bf[2];
#pragma unroll
            for (int ms = 0; ms < 4; ms++)
                af[ms] = *(const v4i*)&lA[(wm * 128 + ms * 32 + m0) * BK +
                                          (((cb + chi) ^ rsw) << 4)];
#pragma unroll
            for (int ns = 0; ns < 2; ns++)
                bf[ns] = *(const v4i*)&lB[(wn * 64 + ns * 32 + m0) * BK +
                                          (((cb + chi) ^ rsw) << 4)];

#pragma unroll
            for (int ms = 0; ms < 4; ms++)
#pragma unroll
                for (int ns = 0; ns < 2; ns++)
                    acc[ms][ns] = __builtin_amdgcn_mfma_i32_32x32x32_i8(
                        af[ms], bf[ns], acc[ms][ns], 0, 0, 0);
        }
        __syncthreads();
    }

    // --- epilogue: requantize, store int32
    // C/D layout (32x32): col = lane&31, row = (reg&3) + 8*(reg>>2) + 4*(lane>>5)
    const float inv_os = 1.0f / *oscale_p;
    const int ozp = *ozp_p;
    const int rbase = 4 * (lane >> 5);
#pragma unroll
    for (int ns = 0; ns < 2; ns++) {
        const int gn = bn + wn * 64 + ns * 32 + m0;
        const int bv = bias[gn];
#pragma unroll
        for (int ms = 0; ms < 4; ms++) {
            const int gm0 = bm + wm * 128 + ms * 32 + rbase;
            v16i a = acc[ms][ns];
#pragma unroll
            for (int reg = 0; reg < 16; reg++) {
                const int row = (reg & 3) + 8 * (reg >> 2);
                int v = a[reg] + bv;
                int q = (int)rintf((float)v * inv_os) + ozp;
                q = clamp_i8(q);
                C[(int64_t)(gm0 + row) * M + gn] = q;
            }
        }
    }
}

extern "C" void kernel_launch(void* const* d_in, const int* in_sizes, int n_in,
                              void* d_out, int out_size, void* d_ws, size_t ws_size,
                              hipStream_t stream) {
    const float* x = (const float*)d_in[0];
    const int* wgt = (const int*)d_in[1];
    const int* bias = (const int*)d_in[2];
    const float* in_scale = (const float*)d_in[3];
    const int* in_zp = (const int*)d_in[4];
    const float* out_scale = (const float*)d_in[5];
    const int* out_zp = (const int*)d_in[6];

    const int64_t x_elems = (int64_t)in_sizes[0];  // N*K
    const int OUT = in_sizes[2];                   // bias length
    const int K = in_sizes[1] / OUT;               // IN
    const int N = (int)(x_elems / K);

    int8_t* qA = (int8_t*)d_ws;
    int8_t* qW = qA + x_elems;

    {
        int n4 = (int)(x_elems / 4);
        quant_input_kernel<<<(n4 + 255) / 256, 256, 0, stream>>>(x, qA, in_scale, in_zp, n4);
    }
    {
        int n4 = (int)(((int64_t)OUT * K) / 4);
        pack_weight_kernel<<<(n4 + 255) / 256, 256, 0, stream>>>(wgt, qW, n4);
    }
    dim3 grid(OUT / BN, N / BM);
    gemm_i8_kernel<<<grid, 256, 0, stream>>>(qA, qW, bias, (int*)d_out,
                                             out_scale, out_zp, N, K, OUT);
}

// Round 5
// 419.984 us; speedup vs baseline: 1.0553x; 1.0106x over previous
//
#include <hip/hip_runtime.h>
#include <stdint.h>

typedef int v4i __attribute__((ext_vector_type(4)));
typedef int v16i __attribute__((ext_vector_type(16)));

__device__ __forceinline__ int clamp_i8(int v) {
    return v < -128 ? -128 : (v > 127 ? 127 : v);
}

__device__ __forceinline__ void async_load16(const void* g, void* l) {
    __builtin_amdgcn_global_load_lds(
        (const __attribute__((address_space(1))) void*)g,
        (__attribute__((address_space(3))) void*)l, 16, 0, 0);
}

// ---------------- pre-pass 1: quantize fp32 input -> int8 (16 elems/thread) ----
__global__ void quant_input_kernel(const float4* __restrict__ x, int4* __restrict__ q,
                                   const float* __restrict__ scale_p,
                                   const int* __restrict__ zp_p, int n16) {
    int t = blockIdx.x * blockDim.x + threadIdx.x;
    if (t >= n16) return;
    const float inv = 1.0f / *scale_p;
    const int zp = *zp_p;
    int4 out;
    int* op = (int*)&out;
#pragma unroll
    for (int j = 0; j < 4; j++) {
        float4 v = x[4 * t + j];
        int q0 = clamp_i8((int)rintf(v.x * inv) + zp);
        int q1 = clamp_i8((int)rintf(v.y * inv) + zp);
        int q2 = clamp_i8((int)rintf(v.z * inv) + zp);
        int q3 = clamp_i8((int)rintf(v.w * inv) + zp);
        op[j] = (q0 & 255) | ((q1 & 255) << 8) | ((q2 & 255) << 16) | ((q3 & 255) << 24);
    }
    q[t] = out;
}

// ---------------- pre-pass 2: pack int32 weight -> int8 (16 elems/thread) -------
__global__ void pack_weight_kernel(const int4* __restrict__ w, int4* __restrict__ q, int n16) {
    int t = blockIdx.x * blockDim.x + threadIdx.x;
    if (t >= n16) return;
    int4 out;
    int* op = (int*)&out;
#pragma unroll
    for (int j = 0; j < 4; j++) {
        int4 v = w[4 * t + j];
        op[j] = (v.x & 255) | ((v.y & 255) << 8) | ((v.z & 255) << 16) | ((v.w & 255) << 24);
    }
    q[t] = out;
}

// ---------------- main GEMM: C[i][j] = sum_k A[i][k] * W[j][k] ----------------
// 256x128 block tile, BK=64; 4 waves 2x2, wave tile 128x64 via 4x2 of 32x32x32 MFMA.
// XOR-swizzled LDS (chunk c ^ ((r>>1)&3)) to break b128 bank aliasing.
// DOUBLE-BUFFERED: prefetch for tile k+1 issued AFTER barrier k, drained at
// barrier k+1 -> load latency overlapped with a full compute phase.
#define BM 256
#define BN 128
#define BK 64

__global__ __launch_bounds__(256, 2) void gemm_i8_kernel(
    const int8_t* __restrict__ A, const int8_t* __restrict__ W,
    const int* __restrict__ bias, int* __restrict__ C,
    const float* __restrict__ oscale_p, const int* __restrict__ ozp_p,
    int N, int K, int M) {
    __shared__ int8_t lA[2][BM * BK];  // 2 x 16 KiB
    __shared__ int8_t lB[2][BN * BK];  // 2 x  8 KiB

    const int tid = threadIdx.x;
    const int lane = tid & 63;
    const int w = tid >> 6;   // wave 0..3
    const int wm = w >> 1;    // wave row (0..1), tile rows wm*128
    const int wn = w & 1;     // wave col (0..1), tile cols wn*64

    const int bm = blockIdx.y * BM;
    const int bn = blockIdx.x * BN;

    // --- staging: lane l -> LDS row (base + l>>2), physical chunk l&3;
    // global source chunk = (l&3) ^ ((row>>1)&3)  [swizzle at the source]
    const int s_sub = lane >> 2;                                  // 0..15
    const int s_col = (((lane & 3) ^ ((s_sub >> 1) & 3))) * 16;   // swizzled col
    const int8_t* gA = A + (int64_t)(bm + w * 64 + s_sub) * K + s_col;
    const int8_t* gB = W + (int64_t)(bn + w * 32 + s_sub) * K + s_col;
    const int64_t rs = (int64_t)16 * K;   // +16 rows per chunk
    int8_t* lA0 = &lA[0][w * 4096];
    int8_t* lA1 = &lA[1][w * 4096];
    int8_t* lB0 = &lB[0][w * 2048];
    int8_t* lB1 = &lB[1][w * 2048];

    // --- fragment identities (A/B: [m=lane&31][k=(lane>>5)*16+j])
    const int m0 = lane & 31;
    const int rsw = (m0 >> 1) & 3;   // row-swizzle term
    const int chi = lane >> 5;       // k-half chunk contribution

    v16i acc[4][2];
#pragma unroll
    for (int i = 0; i < 4; i++)
#pragma unroll
        for (int j = 0; j < 2; j++)
#pragma unroll
            for (int r = 0; r < 16; r++) acc[i][j][r] = 0;

    // prologue: stage tile 0 into buf 0
    {
        async_load16(gA, lA0);
        async_load16(gA + rs, lA0 + 1024);
        async_load16(gA + 2 * rs, lA0 + 2048);
        async_load16(gA + 3 * rs, lA0 + 3072);
        async_load16(gB, lB0);
        async_load16(gB + rs, lB0 + 1024);
        gA += BK;
        gB += BK;
    }

    int cur = 0;
    for (int kt = 0; kt < K; kt += BK) {
        __syncthreads();  // drains vmcnt -> buf[cur] ready; orders vs prior reads of buf[cur^1]
        if (kt + BK < K) {
            int8_t* dA = cur ? lA0 : lA1;
            int8_t* dB = cur ? lB0 : lB1;
            async_load16(gA, dA);
            async_load16(gA + rs, dA + 1024);
            async_load16(gA + 2 * rs, dA + 2048);
            async_load16(gA + 3 * rs, dA + 3072);
            async_load16(gB, dB);
            async_load16(gB + rs, dB + 1024);
            gA += BK;
            gB += BK;
        }
        const int8_t* cA = &lA[cur][0];
        const int8_t* cB = &lB[cur][0];
#pragma unroll
        for (int k0 = 0; k0 < BK; k0 += 32) {
            const int cb = k0 >> 4;  // 0 or 2
            v4i af[4], bf[2];
#pragma unroll
            for (int ms = 0; ms < 4; ms++)
                af[ms] = *(const v4i*)&cA[(wm * 128 + ms * 32 + m0) * BK +
                                          (((cb + chi) ^ rsw) << 4)];
#pragma unroll
            for (int ns = 0; ns < 2; ns++)
                bf[ns] = *(const v4i*)&cB[(wn * 64 + ns * 32 + m0) * BK +
                                          (((cb + chi) ^ rsw) << 4)];

#pragma unroll
            for (int ms = 0; ms < 4; ms++)
#pragma unroll
                for (int ns = 0; ns < 2; ns++)
                    acc[ms][ns] = __builtin_amdgcn_mfma_i32_32x32x32_i8(
                        af[ms], bf[ns], acc[ms][ns], 0, 0, 0);
        }
        cur ^= 1;
    }

    // --- epilogue: requantize, store int32
    // C/D layout (32x32): col = lane&31, row = (reg&3) + 8*(reg>>2) + 4*(lane>>5)
    const float inv_os = 1.0f / *oscale_p;
    const int ozp = *ozp_p;
    const int rbase = 4 * (lane >> 5);
#pragma unroll
    for (int ns = 0; ns < 2; ns++) {
        const int gn = bn + wn * 64 + ns * 32 + m0;
        const int bv = bias[gn];
#pragma unroll
        for (int ms = 0; ms < 4; ms++) {
            const int gm0 = bm + wm * 128 + ms * 32 + rbase;
            v16i a = acc[ms][ns];
#pragma unroll
            for (int reg = 0; reg < 16; reg++) {
                const int row = (reg & 3) + 8 * (reg >> 2);
                int v = a[reg] + bv;
                int q = (int)rintf((float)v * inv_os) + ozp;
                q = clamp_i8(q);
                C[(int64_t)(gm0 + row) * M + gn] = q;
            }
        }
    }
}

extern "C" void kernel_launch(void* const* d_in, const int* in_sizes, int n_in,
                              void* d_out, int out_size, void* d_ws, size_t ws_size,
                              hipStream_t stream) {
    const float* x = (const float*)d_in[0];
    const int* wgt = (const int*)d_in[1];
    const int* bias = (const int*)d_in[2];
    const float* in_scale = (const float*)d_in[3];
    const int* in_zp = (const int*)d_in[4];
    const float* out_scale = (const float*)d_in[5];
    const int* out_zp = (const int*)d_in[6];

    const int64_t x_elems = (int64_t)in_sizes[0];  // N*K
    const int OUT = in_sizes[2];                   // bias length
    const int K = in_sizes[1] / OUT;               // IN
    const int N = (int)(x_elems / K);

    int8_t* qA = (int8_t*)d_ws;
    int8_t* qW = qA + x_elems;

    {
        int n16 = (int)(x_elems / 16);
        quant_input_kernel<<<(n16 + 255) / 256, 256, 0, stream>>>(
            (const float4*)x, (int4*)qA, in_scale, in_zp, n16);
    }
    {
        int n16 = (int)(((int64_t)OUT * K) / 16);
        pack_weight_kernel<<<(n16 + 255) / 256, 256, 0, stream>>>(
            (const int4*)wgt, (int4*)qW, n16);
    }
    dim3 grid(OUT / BN, N / BM);
    gemm_i8_kernel<<<grid, 256, 0, stream>>>(qA, qW, bias, (int*)d_out,
                                             out_scale, out_zp, N, K, OUT);
}